// Round 12
// baseline (767.402 us; speedup 1.0000x reference)
//
#include <hip/hip_runtime.h>

// LSTM T=2048,B=2048,H=32,I=1,O=1 fused in ONE kernel.
// R12: one wave64 per batch element at 2 waves/SIMD, with R7-like issue
// efficiency. Lane pairing: lane 2j computes gates {i,f} of unit j over the
// FULL k=32 dot (no k-combine); lane 2j+1 computes {g,o}. The activation
// exchange is one quad_perm[1,0,3,2] DPP pair (adjacent-lane swap, pure
// VALU, 2 cyc) -- unlike R8's k-split (4 dpp k-combines + duplicated trans)
// or R2's cross-32 bpermute. Trans/lane: 4 own gates + 2 tanh(c).
// Why: R7/R10 bottomed at ~540 cyc issue + ~300 cyc exposed chain (LDS
// turnaround + trans chain) at 1 wave/SIMD. 2048 waves = 2 waves/SIMD lets
// the co-resident wave's issue cover the chain (R8 proved the mechanism:
// VALUBusy 66->80; it lost on per-element issue, which this fixes).
// f32 throughout; pre-scaled weights (no dependent mul before exp2);
// c kept pre-scaled by 2*log2e; x via single v_readlane; O=1 projection via
// 6-step DPP tree, store from lane 63.

namespace {
constexpr int T_ = 2048;
constexpr int B_ = 2048;
constexpr int H_ = 32;
constexpr int WPB = 4;              // waves (= elements) per block
constexpr int CHUNK = 64;           // timesteps of x held in one VGPR
constexpr int NCH = T_ / CHUNK;     // 32
constexpr int OUTS = T_ * B_;       // floats of outs [T,B,1]
constexpr float L2E = 1.442695040888963f;  // log2(e)

typedef float v2f __attribute__((ext_vector_type(2)));
typedef float v4f __attribute__((ext_vector_type(4)));

__device__ __forceinline__ float rcp_(float v){ return __builtin_amdgcn_rcpf(v); }
__device__ __forceinline__ float ex2_(float v){ return __builtin_amdgcn_exp2f(v); }

template <int CTRL, int RM, int BM, bool BC>
__device__ __forceinline__ float dpp_movf(float src) {
    return __builtin_bit_cast(float,
        __builtin_amdgcn_update_dpp(0, __builtin_bit_cast(int, src),
                                    CTRL, RM, BM, BC));
}
template <int CTRL, int RM, int BM, bool BC>
__device__ __forceinline__ float dpp_add(float acc, float src) {
    return acc + dpp_movf<CTRL,RM,BM,BC>(src);
}
// Sum over all 64 lanes; result valid in lane 63.
__device__ __forceinline__ float wave_sum64(float v) {
    v = dpp_add<0x111,0xF,0xF,true >(v, v);  // row_shr:1
    v = dpp_add<0x112,0xF,0xF,true >(v, v);  // row_shr:2
    v = dpp_add<0x114,0xF,0xF,true >(v, v);  // row_shr:4
    v = dpp_add<0x118,0xF,0xF,true >(v, v);  // row_shr:8  -> lanes 15/31/47/63
    v = dpp_add<0x142,0xA,0xF,false>(v, v);  // row_bcast:15 -> lane31=rows0-1, 63=rows2-3
    v = dpp_add<0x143,0x8,0xF,false>(v, v);  // row_bcast:31 -> lane63=all 64
    return v;
}
} // namespace

__global__ __launch_bounds__(256, 2) void lstm_fused12(
    const float* __restrict__ x,      // [T,B,1]
    const float* __restrict__ W_ih,   // [4H,1]
    const float* __restrict__ W_hh,   // [4H,H]
    const float* __restrict__ b_ih,   // [4H]
    const float* __restrict__ b_hh,   // [4H]
    const float* __restrict__ W_out,  // [1,H]
    const float* __restrict__ b_out,  // [1]
    float* __restrict__ out)          // outs | hT | cT
{
    const int l  = threadIdx.x & 63;
    const int wv = threadIdx.x >> 6;
    const int j  = l >> 1;            // hidden unit (2 lanes per unit)
    const int gp = l & 1;             // 0: gates {i,f}   1: gates {g,o}
    const int e  = blockIdx.x * WPB + wv;
    const bool odd = (gp != 0);

    __shared__ __align__(16) float hbuf[WPB][H_];

    // Gate rows this lane owns: A = i|g, B = f|o. Pre-scale so exp2 needs no
    // dependent mul: sigmoid -> -L2E; tanh(g) pre-scaled-for-c2 -> 2*L2E.
    const int gA = gp * 2;            // 0 (i) or 2 (g)
    const int gB = gp * 2 + 1;        // 1 (f) or 3 (o)
    const float sA = odd ? 2.0f*L2E : -L2E;
    const float sB = -L2E;
    // act for gate A: odd lane produces gv2 = 2L2E*tanh(aG) directly:
    //   act = cA0 + cA1 * rcp(1+exp2(a))
    const float cA0 = odd ? 2.0f*L2E : 0.0f;
    const float cA1 = odd ? -4.0f*L2E : 1.0f;

    v2f wA[H_/2], wB[H_/2];
#pragma unroll
    for (int k2 = 0; k2 < H_/2; ++k2) {
        const float* rA = W_hh + (gA*H_ + j) * H_;
        const float* rB = W_hh + (gB*H_ + j) * H_;
        wA[k2] = (v2f){ rA[2*k2] * sA, rA[2*k2+1] * sA };
        wB[k2] = (v2f){ rB[2*k2] * sB, rB[2*k2+1] * sB };
    }
#pragma unroll
    for (int k2 = 0; k2 < H_/2; ++k2) {   // init-time pins
        __asm__ __volatile__("" : "+v"(wA[k2]), "+v"(wB[k2]));
    }

    const float wxA = W_ih[gA*H_+j] * sA;
    const float wxB = W_ih[gB*H_+j] * sB;
    const float bA  = (b_ih[gA*H_+j] + b_hh[gA*H_+j]) * sA;
    const float bB  = (b_ih[gB*H_+j] + b_hh[gB*H_+j]) * sB;
    const float woutM = odd ? 0.0f : W_out[j];   // odd lanes contribute 0
    const float bout  = b_out[0];

    float c2 = 0.0f, h = 0.0f;           // c2 = 2*L2E * c
    hbuf[wv][j] = 0.0f;                  // h0 = 0 (pair writes same value)
    __asm__ __volatile__("" ::: "memory");
    v4f hq[H_/4];
#pragma unroll
    for (int q = 0; q < H_/4; ++q)       // h_0 fragments for step 0
        hq[q] = ((const v4f*)&hbuf[wv][0])[q];

    float xcur = x[l * B_ + e];          // chunk 0: lane l holds t=l
    int outOff = e;                      // out[t*B_ + e]

    for (int ch = 0; ch < NCH; ++ch) {
        float xnext = 0.0f;
        if (ch + 1 < NCH) xnext = x[((ch+1)*CHUNK + l) * B_ + e];
#pragma unroll 8
        for (int s = 0; s < CHUNK; ++s) {
            // x broadcast: single readlane (whole wave is one element)
            const float xk = __builtin_bit_cast(float,
                __builtin_amdgcn_readlane(__builtin_bit_cast(int, xcur), s));
            // full-k dots for this lane's 2 gates; acc0 starts at x-term
            v2f aA0 = {bA + xk*wxA, 0.f}, aA1 = {0.f, 0.f};
            v2f aB0 = {bB + xk*wxB, 0.f}, aB1 = {0.f, 0.f};
#pragma unroll
            for (int q = 0; q < H_/4; ++q) {
                const v2f hlo = (v2f){ hq[q].x, hq[q].y };
                const v2f hhi = (v2f){ hq[q].z, hq[q].w };
                aA0 += wA[2*q] * hlo;  aA1 += wA[2*q+1] * hhi;
                aB0 += wB[2*q] * hlo;  aB1 += wB[2*q+1] * hhi;
            }
            const v2f aAv = aA0 + aA1, aBv = aB0 + aB1;
            const float aA = aAv.x + aAv.y;
            const float aB = aBv.x + aBv.y;
            // own activations: A = sigmoid(i) | gv2=2L2E*tanh(g); B = sigmoid
            const float actA = cA0 + cA1 * rcp_(1.0f + ex2_(aA));
            const float actB = rcp_(1.0f + ex2_(aB));
            // adjacent-lane exchange (quad_perm [1,0,3,2]): pure VALU
            const float nA = dpp_movf<0xB1,0xF,0xF,true>(actA);
            const float nB = dpp_movf<0xB1,0xF,0xF,true>(actB);
            const float iv  = odd ? nA : actA;
            const float fv  = odd ? nB : actB;
            const float gv2 = odd ? actA : nA;
            const float ov  = odd ? actB : nB;
            c2 = fv * c2 + iv * gv2;                       // c2 = 2L2E*c
            const float tc = 1.0f - 2.0f * rcp_(1.0f + ex2_(c2));
            h = ov * tc;
            hbuf[wv][j] = h;          // pair writes same value (2-way: free)
            __asm__ __volatile__("" ::: "memory");
            // issue NEXT step's h reads now; projection below hides latency
#pragma unroll
            for (int q = 0; q < H_/4; ++q)
                hq[q] = ((const v4f*)&hbuf[wv][0])[q];
            // O=1 projection: 6-step DPP tree, total lands in lane 63
            const float pr = wave_sum64(h * woutM);
            if (l == 63) out[outOff] = pr + bout;
            outOff += B_;
        }
        xcur = xnext;
    }
    // Final states: hT [1,B,H] then cT [1,B,H] (even lane of each pair)
    if (!odd) {
        out[OUTS + e*H_ + j] = h;
        out[OUTS + B_*H_ + e*H_ + j] = c2 * (0.5f / L2E);
    }
}

extern "C" void kernel_launch(void* const* d_in, const int* in_sizes, int n_in,
                              void* d_out, int out_size, void* d_ws, size_t ws_size,
                              hipStream_t stream) {
    const float* x     = (const float*)d_in[0];
    const float* W_ih  = (const float*)d_in[1];
    const float* W_hh  = (const float*)d_in[2];
    const float* b_ih  = (const float*)d_in[3];
    const float* b_hh  = (const float*)d_in[4];
    const float* W_out = (const float*)d_in[5];
    const float* b_out = (const float*)d_in[6];
    lstm_fused12<<<dim3(B_ / WPB), dim3(WPB * 64), 0, stream>>>(
        x, W_ih, W_hh, b_ih, b_hh, W_out, b_out, (float*)d_out);
}

// Round 13
// 712.742 us; speedup vs baseline: 1.0767x; 1.0767x over previous
//
#include <hip/hip_runtime.h>

// LSTM T=2048,B=2048,H=32,I=1,O=1 fused in ONE kernel.
// R13 = R10 (712us champion, re-locked) + one arithmetically-identical
// chain trim: h = fma(-2*ov, r, ov) with -2*ov computed parallel to the
// rcp, removing one dependent mul from the per-step tail.
// Final structure (measured best across 12 rounds):
//   wave64 = 2 batch elements in lockstep 32-lane halves; lane owns unit
//   j=l&31 of its half's element and computes all 4 gates (minimal
//   issue/element: 270 cyc). f32 throughout (f16 failed accuracy: 1.66e-2
//   vs 1.01e-2 threshold). LDS h broadcast (8x ds_read_b128, latency
//   covered by projection + x-term work). Activation exp2 scales pre-baked
//   into weights/biases. O=1 projection via pure-VALU DPP tree. x broadcast
//   via v_readlane. 1024 waves = 1/SIMD (2-wave stacking measured worse:
//   R8 835, R12 767 -- per-element issue bloat exceeds bubble fill).
// Floor accounting: 834 cyc/step = 540 issue (256 irreducible f32 dot +
// 80 trans + misc) + ~295 exposed recurrence latency. Alternatives
// measured worse: DPP-gather 792, k-split 835, gate-split 767, f16 FAIL.

namespace {
constexpr int T_ = 2048;
constexpr int B_ = 2048;
constexpr int H_ = 32;
constexpr int WPB = 4;              // waves per block; each wave = 2 elements
constexpr int EPB = WPB * 2;        // batch elements per block
constexpr int CHUNK = 32;           // timesteps of x held in one VGPR
constexpr int NCH = T_ / CHUNK;     // 64
constexpr int OUTS = T_ * B_;       // floats of outs [T,B,1]
constexpr float L2E = 1.442695040888963f;  // log2(e)

typedef float v2f __attribute__((ext_vector_type(2)));
typedef float v4f __attribute__((ext_vector_type(4)));

__device__ __forceinline__ float rcp_(float v){ return __builtin_amdgcn_rcpf(v); }
__device__ __forceinline__ float ex2_(float v){ return __builtin_amdgcn_exp2f(v); }

template <int CTRL, int RM, int BM, bool BC>
__device__ __forceinline__ float dpp_add(float acc, float src) {
    int mv = __builtin_amdgcn_update_dpp(0, __builtin_bit_cast(int, src),
                                         CTRL, RM, BM, BC);
    return acc + __builtin_bit_cast(float, mv);
}
// Sum within each 32-lane half; result in lane 31 (half0) / lane 63 (half1).
__device__ __forceinline__ float half_sum32(float v) {
    v = dpp_add<0x111, 0xF, 0xF, true >(v, v);  // row_shr:1
    v = dpp_add<0x112, 0xF, 0xF, true >(v, v);  // row_shr:2
    v = dpp_add<0x114, 0xF, 0xF, true >(v, v);  // row_shr:4
    v = dpp_add<0x118, 0xF, 0xF, true >(v, v);  // row_shr:8
    v = dpp_add<0x142, 0xA, 0xF, false>(v, v);  // row_bcast:15 -> rows 1,3
    return v;
}
} // namespace

__global__ __launch_bounds__(256, 1)
__attribute__((amdgpu_num_vgpr(256)))
void lstm_fused13(
    const float* __restrict__ x,      // [T,B,1]
    const float* __restrict__ W_ih,   // [4H,1]
    const float* __restrict__ W_hh,   // [4H,H]
    const float* __restrict__ b_ih,   // [4H]
    const float* __restrict__ b_hh,   // [4H]
    const float* __restrict__ W_out,  // [1,H]
    const float* __restrict__ b_out,  // [1]
    float* __restrict__ out)          // outs | hT | cT
{
    const int l  = threadIdx.x & 63;
    const int wv = threadIdx.x >> 6;
    const int j  = l & 31;            // hidden unit
    const int p  = l >> 5;            // element half within wave
    const int e  = blockIdx.x * EPB + wv * 2 + p;

    __shared__ __align__(16) float hbuf[WPB][2][H_];

    const float sI = -L2E, sF = -L2E, sG = 2.0f * L2E, sO = -L2E;

    // W_hh rows j (i), j+H (f), j+2H (g), j+3H (o); packed k-pairs, pre-scaled
    // so activations need no dependent mul before exp2.
    v2f wi[H_/2], wf[H_/2], wg[H_/2], wo[H_/2];
#pragma unroll
    for (int k2 = 0; k2 < H_/2; ++k2) {
        const float* ri = W_hh + (0*H_ + j) * H_;
        const float* rf = W_hh + (1*H_ + j) * H_;
        const float* rg = W_hh + (2*H_ + j) * H_;
        const float* ro = W_hh + (3*H_ + j) * H_;
        wi[k2] = (v2f){ ri[2*k2] * sI, ri[2*k2+1] * sI };
        wf[k2] = (v2f){ rf[2*k2] * sF, rf[2*k2+1] * sF };
        wg[k2] = (v2f){ rg[2*k2] * sG, rg[2*k2+1] * sG };
        wo[k2] = (v2f){ ro[2*k2] * sO, ro[2*k2+1] * sO };
    }
#pragma unroll
    for (int k2 = 0; k2 < H_/2; ++k2) {       // init-time pins
        __asm__ __volatile__("" : "+v"(wi[k2]));
        __asm__ __volatile__("" : "+v"(wf[k2]));
        __asm__ __volatile__("" : "+v"(wg[k2]));
        __asm__ __volatile__("" : "+v"(wo[k2]));
    }

    const float wxi = W_ih[0*H_+j] * sI, wxf = W_ih[1*H_+j] * sF;
    const float wxg = W_ih[2*H_+j] * sG, wxo = W_ih[3*H_+j] * sO;
    const float bi  = (b_ih[0*H_+j] + b_hh[0*H_+j]) * sI;
    const float bf  = (b_ih[1*H_+j] + b_hh[1*H_+j]) * sF;
    const float bg  = (b_ih[2*H_+j] + b_hh[2*H_+j]) * sG;
    const float bo_ = (b_ih[3*H_+j] + b_hh[3*H_+j]) * sO;
    const float wout = W_out[j];
    const float bout = b_out[0];

    float c = 0.0f, h = 0.0f;
    hbuf[wv][p][j] = 0.0f;               // h0 = 0
    __asm__ __volatile__("" ::: "memory");
    v4f hq[H_/4];
#pragma unroll
    for (int q = 0; q < H_/4; ++q)       // h_0 fragments for step 0
        hq[q] = ((const v4f*)&hbuf[wv][p][0])[q];

    float xcur = x[j * B_ + e];          // chunk 0: lane j holds t=j
    int outOff = e;                      // running offset: out[t*B_+e]

    for (int ch = 0; ch < NCH; ++ch) {
        float xnext = 0.0f;
        if (ch + 1 < NCH) xnext = x[((ch + 1) * CHUNK + j) * B_ + e];
#pragma unroll 8
        for (int s = 0; s < CHUNK; ++s) {
            // x broadcast: register readlane (h-independent, off the chain)
            const int xr0 = __builtin_amdgcn_readlane(__builtin_bit_cast(int, xcur), s);
            const int xr1 = __builtin_amdgcn_readlane(__builtin_bit_cast(int, xcur), s + 32);
            const float xk = p ? __builtin_bit_cast(float, xr1)
                               : __builtin_bit_cast(float, xr0);
            // dot accumulators start at the x-term (saves the merge adds)
            v2f ai0 = {bi  + xk * wxi, 0.f}, ai1 = {0.f, 0.f};
            v2f af0 = {bf  + xk * wxf, 0.f}, af1 = {0.f, 0.f};
            v2f ag0 = {bg  + xk * wxg, 0.f}, ag1 = {0.f, 0.f};
            v2f ao0 = {bo_ + xk * wxo, 0.f}, ao1 = {0.f, 0.f};
#pragma unroll
            for (int q = 0; q < H_/4; ++q) {
                const v2f hlo = (v2f){ hq[q].x, hq[q].y };
                const v2f hhi = (v2f){ hq[q].z, hq[q].w };
                ai0 += wi[2*q] * hlo;  ai1 += wi[2*q+1] * hhi;
                af0 += wf[2*q] * hlo;  af1 += wf[2*q+1] * hhi;
                ag0 += wg[2*q] * hlo;  ag1 += wg[2*q+1] * hhi;
                ao0 += wo[2*q] * hlo;  ao1 += wo[2*q+1] * hhi;
            }
            const v2f ai = ai0 + ai1, af = af0 + af1;
            const v2f ag = ag0 + ag1, ao = ao0 + ao1;
            const float iv = rcp_(1.0f + ex2_(ai.x + ai.y));
            const float fv = rcp_(1.0f + ex2_(af.x + af.y));
            const float gv = 1.0f - 2.0f * rcp_(1.0f + ex2_(ag.x + ag.y));
            const float ov = rcp_(1.0f + ex2_(ao.x + ao.y));
            c = fv * c + iv * gv;
            // tail trim: h = ov*(1-2r) = fma(-2*ov, r, ov); -2*ov computes
            // in parallel with the rcp -> chain is rcp -> fma (was rcp ->
            // fma -> mul).
            const float ovm2 = -2.0f * ov;
            const float r    = rcp_(1.0f + ex2_((2.0f * L2E) * c));
            h = ovm2 * r + ov;
            hbuf[wv][p][j] = h;           // publish h_t
            __asm__ __volatile__("" ::: "memory");
            // issue NEXT step's h reads immediately; work below hides latency
#pragma unroll
            for (int q = 0; q < H_/4; ++q)
                hq[q] = ((const v4f*)&hbuf[wv][p][0])[q];
            // output projection: DPP half-sum (pure VALU, no lgkm waits)
            const float pr = half_sum32(h * wout);
            if ((l & 31) == 31) out[outOff] = pr + bout;
            outOff += B_;
        }
        xcur = xnext;
    }
    // Final states: hT [1,B,H] then cT [1,B,H] — valid on every lane.
    out[OUTS + e * H_ + j] = h;
    out[OUTS + B_ * H_ + e * H_ + j] = c;
}

extern "C" void kernel_launch(void* const* d_in, const int* in_sizes, int n_in,
                              void* d_out, int out_size, void* d_ws, size_t ws_size,
                              hipStream_t stream) {
    const float* x     = (const float*)d_in[0];
    const float* W_ih  = (const float*)d_in[1];
    const float* W_hh  = (const float*)d_in[2];
    const float* b_ih  = (const float*)d_in[3];
    const float* b_hh  = (const float*)d_in[4];
    const float* W_out = (const float*)d_in[5];
    const float* b_out = (const float*)d_in[6];
    lstm_fused13<<<dim3(B_ / EPB), dim3(256), 0, stream>>>(
        x, W_ih, W_hh, b_ih, b_hh, W_out, b_out, (float*)d_out);
}